// Round 1
// baseline (442.100 us; speedup 1.0000x reference)
//
#include <hip/hip_runtime.h>
#include <hip/hip_bf16.h>
#include <math.h>

// Problem constants
#define B_SZ 2
#define S_SZ 512
#define T_TOK 1024   // B*S
#define H_DIM 1024
#define I_DIM 4096
#define E_NUM 8

typedef __attribute__((ext_vector_type(8))) short bf16x8;
typedef __attribute__((ext_vector_type(4))) float f32x4;

#define MFMA_BF16(a, b, c) __builtin_amdgcn_mfma_f32_16x16x32_bf16(a, b, c, 0, 0, 0)

__device__ inline short f2bf(float f) {
  union { float f; unsigned u; } x; x.f = f;
  unsigned r = (x.u + 0x7fffu + ((x.u >> 16) & 1u)) >> 16;
  return (short)r;
}
__device__ inline int pack2bf(float a, float b) {
  return ((int)(unsigned short)f2bf(a)) | (((int)f2bf(b)) << 16);
}

// ---------------- K0: zero counters ----------------
__global__ void k_init(int* counts, float* usage) {
  int i = threadIdx.x;
  if (i < E_NUM) { counts[i] = 0; usage[i] = 0.f; }
}

// ---------------- K1: LayerNorm + router + top2 + lists ----------------
__global__ __launch_bounds__(256) void k_ln_router(
    const float* __restrict__ x, const float* __restrict__ ln_w,
    const float* __restrict__ ln_b, const float* __restrict__ Wr,
    const float* __restrict__ br,
    short* __restrict__ xln, int* __restrict__ counts, float* __restrict__ usage,
    int* __restrict__ tlist, int* __restrict__ sel_e, int* __restrict__ sel_idx,
    float* __restrict__ sel_w) {
  const int t = blockIdx.x;
  const int tid = threadIdx.x;
  const int lane = tid & 63, wid = tid >> 6;
  __shared__ float sx[H_DIM];
  __shared__ float redS[8];
  __shared__ float slog[E_NUM];

  float4 v = ((const float4*)(x + (size_t)t * H_DIM))[tid];
  float s = v.x + v.y + v.z + v.w;
  float ss = v.x * v.x + v.y * v.y + v.z * v.z + v.w * v.w;
  for (int o = 32; o > 0; o >>= 1) { s += __shfl_down(s, o); ss += __shfl_down(ss, o); }
  if (lane == 0) { redS[wid] = s; redS[4 + wid] = ss; }
  __syncthreads();
  float st = redS[0] + redS[1] + redS[2] + redS[3];
  float sst = redS[4] + redS[5] + redS[6] + redS[7];
  float mu = st * (1.0f / H_DIM);
  float var = sst * (1.0f / H_DIM) - mu * mu;
  float rs = rsqrtf(var + 1e-5f);

  float4 lw = ((const float4*)ln_w)[tid];
  float4 lb = ((const float4*)ln_b)[tid];
  float4 xn;
  xn.x = (v.x - mu) * rs * lw.x + lb.x;
  xn.y = (v.y - mu) * rs * lw.y + lb.y;
  xn.z = (v.z - mu) * rs * lw.z + lb.z;
  xn.w = (v.w - mu) * rs * lw.w + lb.w;
  sx[4 * tid + 0] = xn.x; sx[4 * tid + 1] = xn.y;
  sx[4 * tid + 2] = xn.z; sx[4 * tid + 3] = xn.w;
  short4 s4;
  s4.x = f2bf(xn.x); s4.y = f2bf(xn.y); s4.z = f2bf(xn.z); s4.w = f2bf(xn.w);
  ((short4*)(xln + (size_t)t * H_DIM))[tid] = s4;
  __syncthreads();

  // Router logits: wave `wid` handles experts 2*wid, 2*wid+1 (f32 for exact top-k)
  for (int e = 2 * wid; e < 2 * wid + 2; ++e) {
    float p = 0.f;
    for (int h = lane; h < H_DIM; h += 64) p += sx[h] * Wr[e * H_DIM + h];
    for (int o = 32; o > 0; o >>= 1) p += __shfl_down(p, o);
    if (lane == 0) slog[e] = p + br[e];
  }
  __syncthreads();

  if (tid == 0) {
    float lg[E_NUM];
    for (int e = 0; e < E_NUM; ++e) lg[e] = slog[e];
    int i0 = 0;
    for (int e = 1; e < E_NUM; ++e) if (lg[e] > lg[i0]) i0 = e;
    int i1 = (i0 == 0) ? 1 : 0;
    for (int e = 0; e < E_NUM; ++e) if (e != i0 && lg[e] > lg[i1]) i1 = e;
    float w1e = __expf(lg[i1] - lg[i0]);
    float den = 1.f + w1e;
    float w0v = 1.f / den, w1v = w1e / den;
    // full softmax for usage/balance loss
    float se = 0.f, pe[E_NUM];
    for (int e = 0; e < E_NUM; ++e) { pe[e] = __expf(lg[e] - lg[i0]); se += pe[e]; }
    float inv = 1.f / (se * (float)T_TOK);
    for (int e = 0; e < E_NUM; ++e) atomicAdd(&usage[e], pe[e] * inv);
    int idx0 = atomicAdd(&counts[i0], 1);
    tlist[i0 * T_TOK + idx0] = t;
    sel_e[2 * t] = i0; sel_idx[2 * t] = idx0; sel_w[2 * t] = w0v;
    int idx1 = atomicAdd(&counts[i1], 1);
    tlist[i1 * T_TOK + idx1] = t;
    sel_e[2 * t + 1] = i1; sel_idx[2 * t + 1] = idx1; sel_w[2 * t + 1] = w1v;
  }
}

// ---------------- K2: prefix scan + balance loss ----------------
__global__ void k_scan(const int* __restrict__ counts, int* __restrict__ base,
                       const float* __restrict__ usage, float* __restrict__ loss_out) {
  if (threadIdx.x == 0 && blockIdx.x == 0) {
    int b = 0;
    for (int e = 0; e < E_NUM; ++e) { base[e] = b; b += counts[e]; }
    float s = 0.f;
    for (int e = 0; e < E_NUM; ++e) s += usage[e] * usage[e];
    *loss_out = (float)E_NUM * s - 1.0f;
  }
}

// ---------------- K3: per-expert GEMM1 + bias + GELU ----------------
// A = gathered xln [n_e, H] bf16; B = W1[e] [I, H] f32 (NT). 64x64 tile, 4 waves.
__global__ __launch_bounds__(256) void k_ffn1(
    const short* __restrict__ xln, const float* __restrict__ W1,
    const float* __restrict__ b1, const int* __restrict__ counts,
    const int* __restrict__ base, const int* __restrict__ tlist,
    short* __restrict__ a_buf) {
  const int e = blockIdx.z;
  const int cnt = counts[e];
  const int m0 = blockIdx.y * 64;
  if (m0 >= cnt) return;
  const int n0 = blockIdx.x * 64;

  __shared__ __align__(16) short As[64][40];
  __shared__ __align__(16) short Bs[64][40];

  const int tid = threadIdx.x;
  const int row = tid >> 2;
  const int kc = (tid & 3) * 8;

  int mrow = m0 + row; if (mrow > cnt - 1) mrow = cnt - 1;
  const int tok = tlist[e * T_TOK + mrow];
  const short* aptr = xln + (size_t)tok * H_DIM + kc;
  const float* bptr = W1 + ((size_t)e * I_DIM + n0 + row) * H_DIM + kc;

  const int lane = tid & 63;
  const int wid = tid >> 6;
  const int wr = wid >> 1, wc = wid & 1;
  const int fr = lane & 15, fq = lane >> 4;
  const int fk = fq * 8;

  f32x4 acc[2][2];
  for (int i = 0; i < 2; ++i) for (int j = 0; j < 2; ++j) acc[i][j] = (f32x4)0.f;

  for (int k0 = 0; k0 < H_DIM; k0 += 32) {
    *(int4*)&As[row][kc] = *(const int4*)(aptr + k0);
    float4 f0 = *(const float4*)(bptr + k0);
    float4 f1 = *(const float4*)(bptr + k0 + 4);
    int4 bp;
    bp.x = pack2bf(f0.x, f0.y); bp.y = pack2bf(f0.z, f0.w);
    bp.z = pack2bf(f1.x, f1.y); bp.w = pack2bf(f1.z, f1.w);
    *(int4*)&Bs[row][kc] = bp;
    __syncthreads();
    bf16x8 af[2], bfv[2];
    for (int mi = 0; mi < 2; ++mi) af[mi] = *(const bf16x8*)&As[wr * 32 + mi * 16 + fr][fk];
    for (int ni = 0; ni < 2; ++ni) bfv[ni] = *(const bf16x8*)&Bs[wc * 32 + ni * 16 + fr][fk];
    for (int mi = 0; mi < 2; ++mi)
      for (int ni = 0; ni < 2; ++ni)
        acc[mi][ni] = MFMA_BF16(af[mi], bfv[ni], acc[mi][ni]);
    __syncthreads();
  }

  const int slot0 = base[e] + m0;
  for (int mi = 0; mi < 2; ++mi)
    for (int ni = 0; ni < 2; ++ni) {
      int colg = n0 + wc * 32 + ni * 16 + fr;
      float bb = b1[e * I_DIM + colg];
      for (int j = 0; j < 4; ++j) {
        int r = wr * 32 + mi * 16 + fq * 4 + j;
        if (m0 + r < cnt) {
          float vv = acc[mi][ni][j] + bb;
          float g = 0.5f * vv * (1.0f + erff(vv * 0.70710678118654752f));
          a_buf[(size_t)(slot0 + r) * I_DIM + colg] = f2bf(g);
        }
      }
    }
}

// ---------------- K4: per-expert GEMM2 + bias -> y_buf ----------------
// A = a_buf [n_e, I] bf16 (contiguous slots); B = W2[e] [H, I] f32 (NT).
__global__ __launch_bounds__(256) void k_ffn2(
    const short* __restrict__ a_buf, const float* __restrict__ W2,
    const float* __restrict__ b2, const int* __restrict__ counts,
    const int* __restrict__ base, float* __restrict__ y_buf) {
  const int e = blockIdx.z;
  const int cnt = counts[e];
  const int m0 = blockIdx.y * 64;
  if (m0 >= cnt) return;
  const int n0 = blockIdx.x * 64;

  __shared__ __align__(16) short As[64][40];
  __shared__ __align__(16) short Bs[64][40];

  const int tid = threadIdx.x;
  const int row = tid >> 2;
  const int kc = (tid & 3) * 8;

  int mrow = m0 + row; if (mrow > cnt - 1) mrow = cnt - 1;
  const short* aptr = a_buf + (size_t)(base[e] + mrow) * I_DIM + kc;
  const float* bptr = W2 + ((size_t)e * H_DIM + n0 + row) * I_DIM + kc;

  const int lane = tid & 63;
  const int wid = tid >> 6;
  const int wr = wid >> 1, wc = wid & 1;
  const int fr = lane & 15, fq = lane >> 4;
  const int fk = fq * 8;

  f32x4 acc[2][2];
  for (int i = 0; i < 2; ++i) for (int j = 0; j < 2; ++j) acc[i][j] = (f32x4)0.f;

  for (int k0 = 0; k0 < I_DIM; k0 += 32) {
    *(int4*)&As[row][kc] = *(const int4*)(aptr + k0);
    float4 f0 = *(const float4*)(bptr + k0);
    float4 f1 = *(const float4*)(bptr + k0 + 4);
    int4 bp;
    bp.x = pack2bf(f0.x, f0.y); bp.y = pack2bf(f0.z, f0.w);
    bp.z = pack2bf(f1.x, f1.y); bp.w = pack2bf(f1.z, f1.w);
    *(int4*)&Bs[row][kc] = bp;
    __syncthreads();
    bf16x8 af[2], bfv[2];
    for (int mi = 0; mi < 2; ++mi) af[mi] = *(const bf16x8*)&As[wr * 32 + mi * 16 + fr][fk];
    for (int ni = 0; ni < 2; ++ni) bfv[ni] = *(const bf16x8*)&Bs[wc * 32 + ni * 16 + fr][fk];
    for (int mi = 0; mi < 2; ++mi)
      for (int ni = 0; ni < 2; ++ni)
        acc[mi][ni] = MFMA_BF16(af[mi], bfv[ni], acc[mi][ni]);
    __syncthreads();
  }

  const int slot0 = base[e] + m0;
  for (int mi = 0; mi < 2; ++mi)
    for (int ni = 0; ni < 2; ++ni) {
      int colg = n0 + wc * 32 + ni * 16 + fr;
      float bb = b2[e * H_DIM + colg];
      for (int j = 0; j < 4; ++j) {
        int r = wr * 32 + mi * 16 + fq * 4 + j;
        if (m0 + r < cnt) {
          y_buf[(size_t)(slot0 + r) * H_DIM + colg] = acc[mi][ni][j] + bb;
        }
      }
    }
}

// ---------------- K5: residual + weighted combine ----------------
__global__ __launch_bounds__(256) void k_combine(
    const float* __restrict__ hidden, const float* __restrict__ y_buf,
    const int* __restrict__ base, const int* __restrict__ sel_e,
    const int* __restrict__ sel_idx, const float* __restrict__ sel_w,
    float* __restrict__ out) {
  const int t = blockIdx.x;
  const int tid = threadIdx.x;
  int e0 = sel_e[2 * t], e1 = sel_e[2 * t + 1];
  int s0 = base[e0] + sel_idx[2 * t];
  int s1 = base[e1] + sel_idx[2 * t + 1];
  float w0 = sel_w[2 * t], w1 = sel_w[2 * t + 1];
  float4 r = ((const float4*)(hidden + (size_t)t * H_DIM))[tid];
  float4 y0 = ((const float4*)(y_buf + (size_t)s0 * H_DIM))[tid];
  float4 y1 = ((const float4*)(y_buf + (size_t)s1 * H_DIM))[tid];
  float4 o;
  o.x = r.x + w0 * y0.x + w1 * y1.x;
  o.y = r.y + w0 * y0.y + w1 * y1.y;
  o.z = r.z + w0 * y0.z + w1 * y1.z;
  o.w = r.w + w0 * y0.w + w1 * y1.w;
  ((float4*)(out + (size_t)t * H_DIM))[tid] = o;
}

extern "C" void kernel_launch(void* const* d_in, const int* in_sizes, int n_in,
                              void* d_out, int out_size, void* d_ws, size_t ws_size,
                              hipStream_t stream) {
  const float* hidden = (const float*)d_in[0];
  const float* ln_w = (const float*)d_in[1];
  const float* ln_b = (const float*)d_in[2];
  const float* Wr = (const float*)d_in[3];
  const float* br = (const float*)d_in[4];
  const float* W1 = (const float*)d_in[5];
  const float* b1 = (const float*)d_in[6];
  const float* W2 = (const float*)d_in[7];
  const float* b2 = (const float*)d_in[8];
  float* out = (float*)d_out;

  // workspace layout
  char* w = (char*)d_ws;
  int* counts = (int*)(w + 0);
  int* basep = (int*)(w + 256);
  float* usage = (float*)(w + 512);
  int* tlist = (int*)(w + 1024);                       // 8*1024*4 = 32 KB
  int* sel_e = (int*)(w + 1024 + 32768);               // 8 KB
  int* sel_idx = (int*)(w + 1024 + 32768 + 8192);      // 8 KB
  float* sel_w = (float*)(w + 1024 + 32768 + 16384);   // 8 KB
  short* xln = (short*)(w + 65536);                    // 2 MB
  short* a_buf = (short*)(w + 65536 + 2097152);        // 16 MB
  float* y_buf = (float*)(w + 65536 + 2097152 + 16777216);  // 8 MB
  // total ~26.1 MB

  k_init<<<1, 64, 0, stream>>>(counts, usage);
  k_ln_router<<<T_TOK, 256, 0, stream>>>(hidden, ln_w, ln_b, Wr, br, xln, counts,
                                         usage, tlist, sel_e, sel_idx, sel_w);
  k_scan<<<1, 1, 0, stream>>>(counts, basep, usage, out + (size_t)T_TOK * H_DIM);
  k_ffn1<<<dim3(I_DIM / 64, T_TOK / 64, E_NUM), 256, 0, stream>>>(
      xln, W1, b1, counts, basep, tlist, a_buf);
  k_ffn2<<<dim3(H_DIM / 64, T_TOK / 64, E_NUM), 256, 0, stream>>>(
      a_buf, W2, b2, counts, basep, y_buf);
  k_combine<<<T_TOK, 256, 0, stream>>>(hidden, y_buf, basep, sel_e, sel_idx,
                                       sel_w, out);
}

// Round 3
// 296.698 us; speedup vs baseline: 1.4901x; 1.4901x over previous
//
#include <hip/hip_runtime.h>
#include <hip/hip_bf16.h>
#include <math.h>
#include <stdint.h>

// Problem constants
#define T_TOK 1024   // B*S
#define H_DIM 1024
#define I_DIM 4096
#define E_NUM 8
#define NSLOT (2 * T_TOK)   // total (token, expert) slots = T_TOK * K

typedef __attribute__((ext_vector_type(8))) short bf16x8;
typedef __attribute__((ext_vector_type(4))) float f32x4;

#define MFMA_BF16(a, b, c) __builtin_amdgcn_mfma_f32_16x16x32_bf16(a, b, c, 0, 0, 0)

__device__ __forceinline__ short f2bf(float f) {
  union { float f; unsigned u; } x; x.f = f;
  unsigned r = (x.u + 0x7fffu + ((x.u >> 16) & 1u)) >> 16;
  return (short)r;
}
__device__ __forceinline__ int pack2bf(float a, float b) {
  return ((int)(unsigned short)f2bf(a)) | (((int)f2bf(b)) << 16);
}

typedef __attribute__((address_space(3))) unsigned int as3_u32;
typedef const __attribute__((address_space(1))) unsigned int as1_u32c;
__device__ __forceinline__ void glds16(const void* g, void* l) {
  __builtin_amdgcn_global_load_lds((as1_u32c*)g, (as3_u32*)l, 16, 0, 0);
}

// ---------------- K0: zero counters ----------------
__global__ void k_init(int* counts, float* usage) {
  int i = threadIdx.x;
  if (i < E_NUM) { counts[i] = 0; usage[i] = 0.f; }
}

// ---------------- K1: LayerNorm + router + top2 + lists ----------------
__global__ __launch_bounds__(256) void k_ln_router(
    const float* __restrict__ x, const float* __restrict__ ln_w,
    const float* __restrict__ ln_b, const float* __restrict__ Wr,
    const float* __restrict__ br,
    short* __restrict__ xln, int* __restrict__ counts, float* __restrict__ usage,
    int* __restrict__ tlist, int* __restrict__ sel_e, int* __restrict__ sel_idx,
    float* __restrict__ sel_w) {
  const int t = blockIdx.x;
  const int tid = threadIdx.x;
  const int lane = tid & 63, wid = tid >> 6;
  __shared__ float sx[H_DIM];
  __shared__ float redS[8];
  __shared__ float slog[E_NUM];

  float4 v = ((const float4*)(x + (size_t)t * H_DIM))[tid];
  float s = v.x + v.y + v.z + v.w;
  float ss = v.x * v.x + v.y * v.y + v.z * v.z + v.w * v.w;
  for (int o = 32; o > 0; o >>= 1) { s += __shfl_down(s, o); ss += __shfl_down(ss, o); }
  if (lane == 0) { redS[wid] = s; redS[4 + wid] = ss; }
  __syncthreads();
  float st = redS[0] + redS[1] + redS[2] + redS[3];
  float sst = redS[4] + redS[5] + redS[6] + redS[7];
  float mu = st * (1.0f / H_DIM);
  float var = sst * (1.0f / H_DIM) - mu * mu;
  float rs = rsqrtf(var + 1e-5f);

  float4 lw = ((const float4*)ln_w)[tid];
  float4 lb = ((const float4*)ln_b)[tid];
  float4 xn;
  xn.x = (v.x - mu) * rs * lw.x + lb.x;
  xn.y = (v.y - mu) * rs * lw.y + lb.y;
  xn.z = (v.z - mu) * rs * lw.z + lb.z;
  xn.w = (v.w - mu) * rs * lw.w + lb.w;
  sx[4 * tid + 0] = xn.x; sx[4 * tid + 1] = xn.y;
  sx[4 * tid + 2] = xn.z; sx[4 * tid + 3] = xn.w;
  short4 s4;
  s4.x = f2bf(xn.x); s4.y = f2bf(xn.y); s4.z = f2bf(xn.z); s4.w = f2bf(xn.w);
  ((short4*)(xln + (size_t)t * H_DIM))[tid] = s4;
  __syncthreads();

  // Router logits: wave `wid` handles experts 2*wid, 2*wid+1 (f32 for exact top-k)
  for (int e = 2 * wid; e < 2 * wid + 2; ++e) {
    float p = 0.f;
    for (int h = lane; h < H_DIM; h += 64) p += sx[h] * Wr[e * H_DIM + h];
    for (int o = 32; o > 0; o >>= 1) p += __shfl_down(p, o);
    if (lane == 0) slog[e] = p + br[e];
  }
  __syncthreads();

  if (tid == 0) {
    float lg[E_NUM];
    for (int e = 0; e < E_NUM; ++e) lg[e] = slog[e];
    int i0 = 0;
    for (int e = 1; e < E_NUM; ++e) if (lg[e] > lg[i0]) i0 = e;
    int i1 = (i0 == 0) ? 1 : 0;
    for (int e = 0; e < E_NUM; ++e) if (e != i0 && lg[e] > lg[i1]) i1 = e;
    float w1e = __expf(lg[i1] - lg[i0]);
    float den = 1.f + w1e;
    float w0v = 1.f / den, w1v = w1e / den;
    // full softmax for usage/balance loss
    float se = 0.f, pe[E_NUM];
    for (int e = 0; e < E_NUM; ++e) { pe[e] = __expf(lg[e] - lg[i0]); se += pe[e]; }
    float inv = 1.f / (se * (float)T_TOK);
    for (int e = 0; e < E_NUM; ++e) atomicAdd(&usage[e], pe[e] * inv);
    int idx0 = atomicAdd(&counts[i0], 1);
    tlist[i0 * T_TOK + idx0] = t;
    sel_e[2 * t] = i0; sel_idx[2 * t] = idx0; sel_w[2 * t] = w0v;
    int idx1 = atomicAdd(&counts[i1], 1);
    tlist[i1 * T_TOK + idx1] = t;
    sel_e[2 * t + 1] = i1; sel_idx[2 * t + 1] = idx1; sel_w[2 * t + 1] = w1v;
  }
}

// ---------------- K2: prefix scan + balance loss ----------------
__global__ void k_scan(const int* __restrict__ counts, int* __restrict__ base,
                       const float* __restrict__ usage, float* __restrict__ loss_out) {
  if (threadIdx.x == 0 && blockIdx.x == 0) {
    int b = 0;
    for (int e = 0; e < E_NUM; ++e) { base[e] = b; b += counts[e]; }
    float s = 0.f;
    for (int e = 0; e < E_NUM; ++e) s += usage[e] * usage[e];
    *loss_out = (float)E_NUM * s - 1.0f;
  }
}

// ---------------- K3: GEMM1 (gathered xln[bf16] x W1[f32->bf16]) + GELU ----------------
// 128x128 tile, BK=32, 4 waves (2x2), each wave 64x64 (4x4 frags of 16x16x32).
// A via global_load_lds (linear LDS). B reg-staged+prefetched, converted, padded LDS.
__global__ __launch_bounds__(256) void k_ffn1(
    const short* __restrict__ xln, const float* __restrict__ W1,
    const float* __restrict__ b1, const int* __restrict__ counts,
    const int* __restrict__ basep, const int* __restrict__ tlist,
    short* __restrict__ a_buf) {
  const int e = blockIdx.z;
  const int cnt = counts[e];
  const int m0 = blockIdx.y * 128;
  if (m0 >= cnt) return;
  const int n0 = blockIdx.x * 128;

  __shared__ __align__(16) short As[128 * 32];  // 8 KB linear (glds dest)
  __shared__ __align__(16) short Bs[128][40];   // 10 KB padded

  const int tid = threadIdx.x;
  const int lane = tid & 63;
  const int wid = tid >> 6;
  const int wr = wid >> 1, wc = wid & 1;
  const int fr = lane & 15, fq = lane >> 4;

  // ---- A staging (2 segs of 16B per thread, per-lane gather source) ----
  const int arow = tid >> 2;           // 0..63
  const int au = (tid & 3) * 8;        // k element offset
  int r0 = m0 + arow;       if (r0 >= cnt) r0 = cnt - 1;
  int r1 = m0 + 64 + arow;  if (r1 >= cnt) r1 = cnt - 1;
  const short* ag0 = xln + (size_t)tlist[e * T_TOK + r0] * H_DIM + au;
  const short* ag1 = xln + (size_t)tlist[e * T_TOK + r1] * H_DIM + au;
  short* al0 = As + (size_t)tid * 8;
  short* al1 = As + (size_t)(256 + tid) * 8;

  // ---- B staging (4 segs of 16B=4xf32 per thread) ----
  const int bcol = (tid & 7) * 4;      // k (f32) offset within BK
  const int brow = tid >> 3;           // +i*32
  const float* bg = W1 + ((size_t)e * I_DIM + n0 + brow) * H_DIM + bcol;
  float4 breg[4];

#define LOADB(kk)                                                        \
  {                                                                      \
    _Pragma("unroll") for (int i = 0; i < 4; ++i)                        \
        breg[i] = *(const float4*)(bg + (size_t)(i * 32) * H_DIM + (kk));\
  }
#define CVTW()                                                           \
  {                                                                      \
    _Pragma("unroll") for (int i = 0; i < 4; ++i) {                      \
      int2 p;                                                            \
      p.x = pack2bf(breg[i].x, breg[i].y);                               \
      p.y = pack2bf(breg[i].z, breg[i].w);                               \
      *(int2*)&Bs[brow + i * 32][bcol] = p;                              \
    }                                                                    \
  }
#define GLDS(kk)                                                         \
  { glds16(ag0 + (kk), al0); glds16(ag1 + (kk), al1); }

  f32x4 acc[4][4];
#pragma unroll
  for (int i = 0; i < 4; ++i)
#pragma unroll
    for (int j = 0; j < 4; ++j) acc[i][j] = (f32x4)0.f;

  LOADB(0);
  GLDS(0);
  CVTW();
  __syncthreads();

  for (int kt = 0; kt < H_DIM / 32; ++kt) {
    const int kn = (kt + 1) * 32;
    const bool last = (kt == H_DIM / 32 - 1);
    if (!last) LOADB(kn);
    bf16x8 af[4], bb[4];
#pragma unroll
    for (int mi = 0; mi < 4; ++mi)
      af[mi] = *(const bf16x8*)(As + (wr * 64 + mi * 16 + fr) * 32 + fq * 8);
#pragma unroll
    for (int ni = 0; ni < 4; ++ni)
      bb[ni] = *(const bf16x8*)&Bs[wc * 64 + ni * 16 + fr][fq * 8];
#pragma unroll
    for (int mi = 0; mi < 4; ++mi)
#pragma unroll
      for (int ni = 0; ni < 4; ++ni)
        acc[mi][ni] = MFMA_BF16(af[mi], bb[ni], acc[mi][ni]);
    __syncthreads();
    if (!last) {
      GLDS(kn);
      CVTW();
      __syncthreads();
    }
  }

  const int slot0 = basep[e] + m0;
  float b1v[4];
#pragma unroll
  for (int ni = 0; ni < 4; ++ni)
    b1v[ni] = b1[e * I_DIM + n0 + wc * 64 + ni * 16 + fr];
#pragma unroll
  for (int mi = 0; mi < 4; ++mi)
#pragma unroll
    for (int j = 0; j < 4; ++j) {
      int r = wr * 64 + mi * 16 + fq * 4 + j;
      if (m0 + r < cnt) {
        size_t rowoff = (size_t)(slot0 + r) * I_DIM;
#pragma unroll
        for (int ni = 0; ni < 4; ++ni) {
          int colg = n0 + wc * 64 + ni * 16 + fr;
          float vv = acc[mi][ni][j] + b1v[ni];
          float g = 0.5f * vv * (1.0f + erff(vv * 0.70710678118654752f));
          a_buf[rowoff + colg] = f2bf(g);
        }
      }
    }
#undef LOADB
#undef CVTW
#undef GLDS
}

// ---------------- K4: GEMM2 (a_buf[bf16] x W2[f32->bf16]), split-K partials ----------------
__global__ __launch_bounds__(256) void k_ffn2(
    const short* __restrict__ a_buf, const float* __restrict__ W2,
    const int* __restrict__ counts, const int* __restrict__ basep,
    float* __restrict__ y_part, int lg) {
  const int z = blockIdx.z;
  const int e = z >> lg;
  const int kc = z & ((1 << lg) - 1);
  const int CH = I_DIM >> lg;
  const int cnt = counts[e];
  const int m0 = blockIdx.y * 128;
  if (m0 >= cnt) return;
  const int n0 = blockIdx.x * 128;

  __shared__ __align__(16) short As[128 * 32];
  __shared__ __align__(16) short Bs[128][40];

  const int tid = threadIdx.x;
  const int lane = tid & 63;
  const int wid = tid >> 6;
  const int wr = wid >> 1, wc = wid & 1;
  const int fr = lane & 15, fq = lane >> 4;

  const int arow = tid >> 2;
  const int au = (tid & 3) * 8;
  int r0 = m0 + arow;       if (r0 >= cnt) r0 = cnt - 1;
  int r1 = m0 + 64 + arow;  if (r1 >= cnt) r1 = cnt - 1;
  const int sb = basep[e];
  const short* ag0 = a_buf + (size_t)(sb + r0) * I_DIM + kc * CH + au;
  const short* ag1 = a_buf + (size_t)(sb + r1) * I_DIM + kc * CH + au;
  short* al0 = As + (size_t)tid * 8;
  short* al1 = As + (size_t)(256 + tid) * 8;

  const int bcol = (tid & 7) * 4;
  const int brow = tid >> 3;
  const float* bg = W2 + ((size_t)e * H_DIM + n0 + brow) * I_DIM + kc * CH + bcol;
  float4 breg[4];

#define LOADB(kk)                                                        \
  {                                                                      \
    _Pragma("unroll") for (int i = 0; i < 4; ++i)                        \
        breg[i] = *(const float4*)(bg + (size_t)(i * 32) * I_DIM + (kk));\
  }
#define CVTW()                                                           \
  {                                                                      \
    _Pragma("unroll") for (int i = 0; i < 4; ++i) {                      \
      int2 p;                                                            \
      p.x = pack2bf(breg[i].x, breg[i].y);                               \
      p.y = pack2bf(breg[i].z, breg[i].w);                               \
      *(int2*)&Bs[brow + i * 32][bcol] = p;                              \
    }                                                                    \
  }
#define GLDS(kk)                                                         \
  { glds16(ag0 + (kk), al0); glds16(ag1 + (kk), al1); }

  f32x4 acc[4][4];
#pragma unroll
  for (int i = 0; i < 4; ++i)
#pragma unroll
    for (int j = 0; j < 4; ++j) acc[i][j] = (f32x4)0.f;

  LOADB(0);
  GLDS(0);
  CVTW();
  __syncthreads();

  const int KT = CH / 32;
  for (int kt = 0; kt < KT; ++kt) {
    const int kn = (kt + 1) * 32;
    const bool last = (kt == KT - 1);
    if (!last) LOADB(kn);
    bf16x8 af[4], bb[4];
#pragma unroll
    for (int mi = 0; mi < 4; ++mi)
      af[mi] = *(const bf16x8*)(As + (wr * 64 + mi * 16 + fr) * 32 + fq * 8);
#pragma unroll
    for (int ni = 0; ni < 4; ++ni)
      bb[ni] = *(const bf16x8*)&Bs[wc * 64 + ni * 16 + fr][fq * 8];
#pragma unroll
    for (int mi = 0; mi < 4; ++mi)
#pragma unroll
      for (int ni = 0; ni < 4; ++ni)
        acc[mi][ni] = MFMA_BF16(af[mi], bb[ni], acc[mi][ni]);
    __syncthreads();
    if (!last) {
      GLDS(kn);
      CVTW();
      __syncthreads();
    }
  }

  const int slot0 = sb + m0;
  float* yp = y_part + (size_t)kc * ((size_t)NSLOT * H_DIM);
#pragma unroll
  for (int mi = 0; mi < 4; ++mi)
#pragma unroll
    for (int j = 0; j < 4; ++j) {
      int r = wr * 64 + mi * 16 + fq * 4 + j;
      if (m0 + r < cnt) {
        size_t rowoff = (size_t)(slot0 + r) * H_DIM;
#pragma unroll
        for (int ni = 0; ni < 4; ++ni) {
          int colg = n0 + wc * 64 + ni * 16 + fr;
          yp[rowoff + colg] = acc[mi][ni][j];
        }
      }
    }
#undef LOADB
#undef CVTW
#undef GLDS
}

// ---------------- K5: residual + bias + weighted combine over split-K partials ----------------
__global__ __launch_bounds__(256) void k_combine(
    const float* __restrict__ hidden, const float* __restrict__ y_part,
    const float* __restrict__ b2, const int* __restrict__ basep,
    const int* __restrict__ sel_e, const int* __restrict__ sel_idx,
    const float* __restrict__ sel_w, float* __restrict__ out, int KS) {
  const int t = blockIdx.x;
  const int tid = threadIdx.x;
  int e0 = sel_e[2 * t], e1 = sel_e[2 * t + 1];
  int s0 = basep[e0] + sel_idx[2 * t];
  int s1 = basep[e1] + sel_idx[2 * t + 1];
  float w0 = sel_w[2 * t], w1 = sel_w[2 * t + 1];
  const size_t TY = (size_t)NSLOT * H_DIM;   // stride between split-K partial sets
  float4 y0 = make_float4(0.f, 0.f, 0.f, 0.f);
  float4 y1 = make_float4(0.f, 0.f, 0.f, 0.f);
  for (int kc = 0; kc < KS; ++kc) {
    float4 p0 = ((const float4*)(y_part + kc * TY + (size_t)s0 * H_DIM))[tid];
    float4 p1 = ((const float4*)(y_part + kc * TY + (size_t)s1 * H_DIM))[tid];
    y0.x += p0.x; y0.y += p0.y; y0.z += p0.z; y0.w += p0.w;
    y1.x += p1.x; y1.y += p1.y; y1.z += p1.z; y1.w += p1.w;
  }
  float4 be0 = ((const float4*)(b2 + (size_t)e0 * H_DIM))[tid];
  float4 be1 = ((const float4*)(b2 + (size_t)e1 * H_DIM))[tid];
  float4 r = ((const float4*)(hidden + (size_t)t * H_DIM))[tid];
  float4 o;
  o.x = r.x + w0 * (y0.x + be0.x) + w1 * (y1.x + be1.x);
  o.y = r.y + w0 * (y0.y + be0.y) + w1 * (y1.y + be1.y);
  o.z = r.z + w0 * (y0.z + be0.z) + w1 * (y1.z + be1.z);
  o.w = r.w + w0 * (y0.w + be0.w) + w1 * (y1.w + be1.w);
  ((float4*)(out + (size_t)t * H_DIM))[tid] = o;
}

extern "C" void kernel_launch(void* const* d_in, const int* in_sizes, int n_in,
                              void* d_out, int out_size, void* d_ws, size_t ws_size,
                              hipStream_t stream) {
  const float* hidden = (const float*)d_in[0];
  const float* ln_w = (const float*)d_in[1];
  const float* ln_b = (const float*)d_in[2];
  const float* Wr = (const float*)d_in[3];
  const float* br = (const float*)d_in[4];
  const float* W1 = (const float*)d_in[5];
  const float* b1 = (const float*)d_in[6];
  const float* W2 = (const float*)d_in[7];
  const float* b2 = (const float*)d_in[8];
  float* out = (float*)d_out;

  // workspace layout (bytes)
  char* w = (char*)d_ws;
  int* counts = (int*)(w + 0);
  int* basep = (int*)(w + 256);
  float* usage = (float*)(w + 512);
  int* tlist = (int*)(w + 1024);                  // 32 KB
  int* sel_e = (int*)(w + 33792);                 // 8 KB
  int* sel_idx = (int*)(w + 41984);               // 8 KB
  float* sel_w = (float*)(w + 50176);             // 8 KB
  short* xln = (short*)(w + 65536);               // 2 MB
  short* a_buf = (short*)(w + 2162688);           // 16 MB
  float* y_part = (float*)(w + 18939904);         // KS * 8 MB
  const size_t Y_OFF = 18939904;
  const size_t Y_SZ = (size_t)NSLOT * H_DIM * 4;  // 8 MB per split set
  int lg = 2;
  while (lg > 0 && Y_OFF + (Y_SZ << lg) > ws_size) --lg;
  const int KS = 1 << lg;

  k_init<<<1, 64, 0, stream>>>(counts, usage);
  k_ln_router<<<T_TOK, 256, 0, stream>>>(hidden, ln_w, ln_b, Wr, br, xln, counts,
                                         usage, tlist, sel_e, sel_idx, sel_w);
  k_scan<<<1, 1, 0, stream>>>(counts, basep, usage, out + (size_t)T_TOK * H_DIM);
  k_ffn1<<<dim3(I_DIM / 128, T_TOK / 128, E_NUM), 256, 0, stream>>>(
      xln, W1, b1, counts, basep, tlist, a_buf);
  k_ffn2<<<dim3(H_DIM / 128, T_TOK / 128, E_NUM << lg), 256, 0, stream>>>(
      a_buf, W2, counts, basep, y_part, lg);
  k_combine<<<T_TOK, 256, 0, stream>>>(hidden, y_part, b2, basep, sel_e, sel_idx,
                                       sel_w, out, KS);
}

// Round 4
// 200.173 us; speedup vs baseline: 2.2086x; 1.4822x over previous
//
#include <hip/hip_runtime.h>
#include <hip/hip_bf16.h>
#include <math.h>
#include <stdint.h>

// Problem constants
#define T_TOK 1024   // B*S
#define H_DIM 1024
#define I_DIM 4096
#define E_NUM 8
#define NSLOT (2 * T_TOK)   // total (token, expert) slots = T_TOK * K

typedef __attribute__((ext_vector_type(8))) short bf16x8;
typedef __attribute__((ext_vector_type(4))) float f32x4;

#define MFMA_BF16(a, b, c) __builtin_amdgcn_mfma_f32_16x16x32_bf16(a, b, c, 0, 0, 0)

__device__ __forceinline__ short f2bf(float f) {
  union { float f; unsigned u; } x; x.f = f;
  unsigned r = (x.u + 0x7fffu + ((x.u >> 16) & 1u)) >> 16;
  return (short)r;
}
__device__ __forceinline__ int pack2bf(float a, float b) {
  return ((int)(unsigned short)f2bf(a)) | (((int)f2bf(b)) << 16);
}

typedef __attribute__((address_space(3))) unsigned int as3_u32;
typedef const __attribute__((address_space(1))) unsigned int as1_u32c;
__device__ __forceinline__ void glds16(const void* g, void* l) {
  __builtin_amdgcn_global_load_lds((as1_u32c*)g, (as3_u32*)l, 16, 0, 0);
}

// ---------------- K1: LayerNorm + router + top2 (NO atomics) ----------------
__global__ __launch_bounds__(256) void k_ln_router(
    const float* __restrict__ x, const float* __restrict__ ln_w,
    const float* __restrict__ ln_b, const float* __restrict__ Wr,
    const float* __restrict__ br,
    short* __restrict__ xln, int* __restrict__ sel_e, float* __restrict__ sel_w,
    float* __restrict__ probs) {
  const int t = blockIdx.x;
  const int tid = threadIdx.x;
  const int lane = tid & 63, wid = tid >> 6;
  __shared__ float sx[H_DIM];
  __shared__ float redS[8];
  __shared__ float slog[E_NUM];

  float4 v = ((const float4*)(x + (size_t)t * H_DIM))[tid];
  float s = v.x + v.y + v.z + v.w;
  float ss = v.x * v.x + v.y * v.y + v.z * v.z + v.w * v.w;
  for (int o = 32; o > 0; o >>= 1) { s += __shfl_down(s, o); ss += __shfl_down(ss, o); }
  if (lane == 0) { redS[wid] = s; redS[4 + wid] = ss; }
  __syncthreads();
  float st = redS[0] + redS[1] + redS[2] + redS[3];
  float sst = redS[4] + redS[5] + redS[6] + redS[7];
  float mu = st * (1.0f / H_DIM);
  float var = sst * (1.0f / H_DIM) - mu * mu;
  float rs = rsqrtf(var + 1e-5f);

  float4 lw = ((const float4*)ln_w)[tid];
  float4 lb = ((const float4*)ln_b)[tid];
  float4 xn;
  xn.x = (v.x - mu) * rs * lw.x + lb.x;
  xn.y = (v.y - mu) * rs * lw.y + lb.y;
  xn.z = (v.z - mu) * rs * lw.z + lb.z;
  xn.w = (v.w - mu) * rs * lw.w + lb.w;
  sx[4 * tid + 0] = xn.x; sx[4 * tid + 1] = xn.y;
  sx[4 * tid + 2] = xn.z; sx[4 * tid + 3] = xn.w;
  short4 s4;
  s4.x = f2bf(xn.x); s4.y = f2bf(xn.y); s4.z = f2bf(xn.z); s4.w = f2bf(xn.w);
  ((short4*)(xln + (size_t)t * H_DIM))[tid] = s4;
  __syncthreads();

  // Router logits: wave `wid` handles experts 2*wid, 2*wid+1 (f32 for exact top-k)
  for (int e = 2 * wid; e < 2 * wid + 2; ++e) {
    float p = 0.f;
    for (int h = lane; h < H_DIM; h += 64) p += sx[h] * Wr[e * H_DIM + h];
    for (int o = 32; o > 0; o >>= 1) p += __shfl_down(p, o);
    if (lane == 0) slog[e] = p + br[e];
  }
  __syncthreads();

  if (tid == 0) {
    float lg[E_NUM];
    for (int e = 0; e < E_NUM; ++e) lg[e] = slog[e];
    int i0 = 0;
    for (int e = 1; e < E_NUM; ++e) if (lg[e] > lg[i0]) i0 = e;
    int i1 = (i0 == 0) ? 1 : 0;
    for (int e = 0; e < E_NUM; ++e) if (e != i0 && lg[e] > lg[i1]) i1 = e;
    float w1e = __expf(lg[i1] - lg[i0]);
    float den = 1.f + w1e;
    sel_e[2 * t] = i0; sel_w[2 * t] = 1.f / den;
    sel_e[2 * t + 1] = i1; sel_w[2 * t + 1] = w1e / den;
    // full softmax -> probs (normalized), consumed by k_route for usage/loss
    float se = 0.f, pe[E_NUM];
    for (int e = 0; e < E_NUM; ++e) { pe[e] = __expf(lg[e] - lg[i0]); se += pe[e]; }
    float inv = 1.f / se;
    for (int e = 0; e < E_NUM; ++e) probs[t * E_NUM + e] = pe[e] * inv;
  }
}

// ---------------- K2: deterministic slot assignment + counts + loss (1 block) ----------------
__global__ __launch_bounds__(512) void k_route(
    const int* __restrict__ sel_e, const float* __restrict__ probs,
    int* __restrict__ counts, int* __restrict__ basep,
    int* __restrict__ tlist, int* __restrict__ sel_idx,
    float* __restrict__ loss_out) {
  const int wid = threadIdx.x >> 6;   // expert owned by this wave
  const int lane = threadIdx.x & 63;
  __shared__ int scnt[E_NUM];
  __shared__ float susage[E_NUM];

  int cnt = 0;
  for (int s0 = 0; s0 < NSLOT; s0 += 64) {
    int s = s0 + lane;
    bool m = (sel_e[s] == wid);
    unsigned long long mk = __ballot(m);
    int pre = __popcll(mk & ((1ULL << lane) - 1ULL));
    if (m) {
      int idx = cnt + pre;
      sel_idx[s] = idx;
      tlist[wid * T_TOK + idx] = s >> 1;   // token id
    }
    cnt += __popcll(mk);
  }
  if (lane == 0) scnt[wid] = cnt;

  // usage[e] = mean_t probs[t][e]
  float u = 0.f;
  for (int t = lane; t < T_TOK; t += 64) u += probs[t * E_NUM + wid];
  for (int o = 32; o > 0; o >>= 1) u += __shfl_down(u, o);
  if (lane == 0) susage[wid] = u * (1.0f / T_TOK);
  __syncthreads();

  if (threadIdx.x == 0) {
    int b = 0;
    for (int e = 0; e < E_NUM; ++e) { basep[e] = b; counts[e] = scnt[e]; b += scnt[e]; }
    float sq = 0.f;
    for (int e = 0; e < E_NUM; ++e) sq += susage[e] * susage[e];
    *loss_out = (float)E_NUM * sq - 1.0f;
  }
}

// ---------------- K3: GEMM1 (gathered xln[bf16] x W1[f32->bf16]) + GELU ----------------
// 128x128 tile, BK=32, 4 waves (2x2), each wave 64x64 (4x4 frags of 16x16x32).
// A via global_load_lds (linear LDS). B reg-staged+prefetched, converted, padded LDS.
__global__ __launch_bounds__(256) void k_ffn1(
    const short* __restrict__ xln, const float* __restrict__ W1,
    const float* __restrict__ b1, const int* __restrict__ counts,
    const int* __restrict__ basep, const int* __restrict__ tlist,
    short* __restrict__ a_buf) {
  const int e = blockIdx.z;
  const int cnt = counts[e];
  const int m0 = blockIdx.y * 128;
  if (m0 >= cnt) return;
  const int n0 = blockIdx.x * 128;

  __shared__ __align__(16) short As[128 * 32];  // 8 KB linear (glds dest)
  __shared__ __align__(16) short Bs[128][40];   // 10 KB padded

  const int tid = threadIdx.x;
  const int lane = tid & 63;
  const int wid = tid >> 6;
  const int wr = wid >> 1, wc = wid & 1;
  const int fr = lane & 15, fq = lane >> 4;

  // ---- A staging (2 segs of 16B per thread, per-lane gather source) ----
  const int arow = tid >> 2;           // 0..63
  const int au = (tid & 3) * 8;        // k element offset
  int r0 = m0 + arow;       if (r0 >= cnt) r0 = cnt - 1;
  int r1 = m0 + 64 + arow;  if (r1 >= cnt) r1 = cnt - 1;
  const short* ag0 = xln + (size_t)tlist[e * T_TOK + r0] * H_DIM + au;
  const short* ag1 = xln + (size_t)tlist[e * T_TOK + r1] * H_DIM + au;
  short* al0 = As + (size_t)tid * 8;
  short* al1 = As + (size_t)(256 + tid) * 8;

  // ---- B staging (4 segs of 16B=4xf32 per thread) ----
  const int bcol = (tid & 7) * 4;      // k (f32) offset within BK
  const int brow = tid >> 3;           // +i*32
  const float* bg = W1 + ((size_t)e * I_DIM + n0 + brow) * H_DIM + bcol;
  float4 breg[4];

#define LOADB(kk)                                                        \
  {                                                                      \
    _Pragma("unroll") for (int i = 0; i < 4; ++i)                        \
        breg[i] = *(const float4*)(bg + (size_t)(i * 32) * H_DIM + (kk));\
  }
#define CVTW()                                                           \
  {                                                                      \
    _Pragma("unroll") for (int i = 0; i < 4; ++i) {                      \
      int2 p;                                                            \
      p.x = pack2bf(breg[i].x, breg[i].y);                               \
      p.y = pack2bf(breg[i].z, breg[i].w);                               \
      *(int2*)&Bs[brow + i * 32][bcol] = p;                              \
    }                                                                    \
  }
#define GLDS(kk)                                                         \
  { glds16(ag0 + (kk), al0); glds16(ag1 + (kk), al1); }

  f32x4 acc[4][4];
#pragma unroll
  for (int i = 0; i < 4; ++i)
#pragma unroll
    for (int j = 0; j < 4; ++j) acc[i][j] = (f32x4)0.f;

  LOADB(0);
  GLDS(0);
  CVTW();
  __syncthreads();

  for (int kt = 0; kt < H_DIM / 32; ++kt) {
    const int kn = (kt + 1) * 32;
    const bool last = (kt == H_DIM / 32 - 1);
    if (!last) LOADB(kn);
    bf16x8 af[4], bb[4];
#pragma unroll
    for (int mi = 0; mi < 4; ++mi)
      af[mi] = *(const bf16x8*)(As + (wr * 64 + mi * 16 + fr) * 32 + fq * 8);
#pragma unroll
    for (int ni = 0; ni < 4; ++ni)
      bb[ni] = *(const bf16x8*)&Bs[wc * 64 + ni * 16 + fr][fq * 8];
#pragma unroll
    for (int mi = 0; mi < 4; ++mi)
#pragma unroll
      for (int ni = 0; ni < 4; ++ni)
        acc[mi][ni] = MFMA_BF16(af[mi], bb[ni], acc[mi][ni]);
    __syncthreads();
    if (!last) {
      GLDS(kn);
      CVTW();
      __syncthreads();
    }
  }

  const int slot0 = basep[e] + m0;
  float b1v[4];
#pragma unroll
  for (int ni = 0; ni < 4; ++ni)
    b1v[ni] = b1[e * I_DIM + n0 + wc * 64 + ni * 16 + fr];
#pragma unroll
  for (int mi = 0; mi < 4; ++mi)
#pragma unroll
    for (int j = 0; j < 4; ++j) {
      int r = wr * 64 + mi * 16 + fq * 4 + j;
      if (m0 + r < cnt) {
        size_t rowoff = (size_t)(slot0 + r) * I_DIM;
#pragma unroll
        for (int ni = 0; ni < 4; ++ni) {
          int colg = n0 + wc * 64 + ni * 16 + fr;
          float vv = acc[mi][ni][j] + b1v[ni];
          float g = 0.5f * vv * (1.0f + erff(vv * 0.70710678118654752f));
          a_buf[rowoff + colg] = f2bf(g);
        }
      }
    }
#undef LOADB
#undef CVTW
#undef GLDS
}

// ---------------- K4: GEMM2 (a_buf[bf16] x W2[f32->bf16]), split-K partials ----------------
__global__ __launch_bounds__(256) void k_ffn2(
    const short* __restrict__ a_buf, const float* __restrict__ W2,
    const int* __restrict__ counts, const int* __restrict__ basep,
    float* __restrict__ y_part, int lg) {
  const int z = blockIdx.z;
  const int e = z >> lg;
  const int kc = z & ((1 << lg) - 1);
  const int CH = I_DIM >> lg;
  const int cnt = counts[e];
  const int m0 = blockIdx.y * 128;
  if (m0 >= cnt) return;
  const int n0 = blockIdx.x * 128;

  __shared__ __align__(16) short As[128 * 32];
  __shared__ __align__(16) short Bs[128][40];

  const int tid = threadIdx.x;
  const int lane = tid & 63;
  const int wid = tid >> 6;
  const int wr = wid >> 1, wc = wid & 1;
  const int fr = lane & 15, fq = lane >> 4;

  const int arow = tid >> 2;
  const int au = (tid & 3) * 8;
  int r0 = m0 + arow;       if (r0 >= cnt) r0 = cnt - 1;
  int r1 = m0 + 64 + arow;  if (r1 >= cnt) r1 = cnt - 1;
  const int sb = basep[e];
  const short* ag0 = a_buf + (size_t)(sb + r0) * I_DIM + kc * CH + au;
  const short* ag1 = a_buf + (size_t)(sb + r1) * I_DIM + kc * CH + au;
  short* al0 = As + (size_t)tid * 8;
  short* al1 = As + (size_t)(256 + tid) * 8;

  const int bcol = (tid & 7) * 4;
  const int brow = tid >> 3;
  const float* bg = W2 + ((size_t)e * H_DIM + n0 + brow) * I_DIM + kc * CH + bcol;
  float4 breg[4];

#define LOADB(kk)                                                        \
  {                                                                      \
    _Pragma("unroll") for (int i = 0; i < 4; ++i)                        \
        breg[i] = *(const float4*)(bg + (size_t)(i * 32) * I_DIM + (kk));\
  }
#define CVTW()                                                           \
  {                                                                      \
    _Pragma("unroll") for (int i = 0; i < 4; ++i) {                      \
      int2 p;                                                            \
      p.x = pack2bf(breg[i].x, breg[i].y);                               \
      p.y = pack2bf(breg[i].z, breg[i].w);                               \
      *(int2*)&Bs[brow + i * 32][bcol] = p;                              \
    }                                                                    \
  }
#define GLDS(kk)                                                         \
  { glds16(ag0 + (kk), al0); glds16(ag1 + (kk), al1); }

  f32x4 acc[4][4];
#pragma unroll
  for (int i = 0; i < 4; ++i)
#pragma unroll
    for (int j = 0; j < 4; ++j) acc[i][j] = (f32x4)0.f;

  LOADB(0);
  GLDS(0);
  CVTW();
  __syncthreads();

  const int KT = CH / 32;
  for (int kt = 0; kt < KT; ++kt) {
    const int kn = (kt + 1) * 32;
    const bool last = (kt == KT - 1);
    if (!last) LOADB(kn);
    bf16x8 af[4], bb[4];
#pragma unroll
    for (int mi = 0; mi < 4; ++mi)
      af[mi] = *(const bf16x8*)(As + (wr * 64 + mi * 16 + fr) * 32 + fq * 8);
#pragma unroll
    for (int ni = 0; ni < 4; ++ni)
      bb[ni] = *(const bf16x8*)&Bs[wc * 64 + ni * 16 + fr][fq * 8];
#pragma unroll
    for (int mi = 0; mi < 4; ++mi)
#pragma unroll
      for (int ni = 0; ni < 4; ++ni)
        acc[mi][ni] = MFMA_BF16(af[mi], bb[ni], acc[mi][ni]);
    __syncthreads();
    if (!last) {
      GLDS(kn);
      CVTW();
      __syncthreads();
    }
  }

  const int slot0 = sb + m0;
  float* yp = y_part + (size_t)kc * ((size_t)NSLOT * H_DIM);
#pragma unroll
  for (int mi = 0; mi < 4; ++mi)
#pragma unroll
    for (int j = 0; j < 4; ++j) {
      int r = wr * 64 + mi * 16 + fq * 4 + j;
      if (m0 + r < cnt) {
        size_t rowoff = (size_t)(slot0 + r) * H_DIM;
#pragma unroll
        for (int ni = 0; ni < 4; ++ni) {
          int colg = n0 + wc * 64 + ni * 16 + fr;
          yp[rowoff + colg] = acc[mi][ni][j];
        }
      }
    }
#undef LOADB
#undef CVTW
#undef GLDS
}

// ---------------- K5: residual + bias + weighted combine over split-K partials ----------------
__global__ __launch_bounds__(256) void k_combine(
    const float* __restrict__ hidden, const float* __restrict__ y_part,
    const float* __restrict__ b2, const int* __restrict__ basep,
    const int* __restrict__ sel_e, const int* __restrict__ sel_idx,
    const float* __restrict__ sel_w, float* __restrict__ out, int KS) {
  const int t = blockIdx.x;
  const int tid = threadIdx.x;
  int e0 = sel_e[2 * t], e1 = sel_e[2 * t + 1];
  int s0 = basep[e0] + sel_idx[2 * t];
  int s1 = basep[e1] + sel_idx[2 * t + 1];
  float w0 = sel_w[2 * t], w1 = sel_w[2 * t + 1];
  const size_t TY = (size_t)NSLOT * H_DIM;   // stride between split-K partial sets
  float4 y0 = make_float4(0.f, 0.f, 0.f, 0.f);
  float4 y1 = make_float4(0.f, 0.f, 0.f, 0.f);
  for (int kc = 0; kc < KS; ++kc) {
    float4 p0 = ((const float4*)(y_part + kc * TY + (size_t)s0 * H_DIM))[tid];
    float4 p1 = ((const float4*)(y_part + kc * TY + (size_t)s1 * H_DIM))[tid];
    y0.x += p0.x; y0.y += p0.y; y0.z += p0.z; y0.w += p0.w;
    y1.x += p1.x; y1.y += p1.y; y1.z += p1.z; y1.w += p1.w;
  }
  float4 be0 = ((const float4*)(b2 + (size_t)e0 * H_DIM))[tid];
  float4 be1 = ((const float4*)(b2 + (size_t)e1 * H_DIM))[tid];
  float4 r = ((const float4*)(hidden + (size_t)t * H_DIM))[tid];
  float4 o;
  o.x = r.x + w0 * (y0.x + be0.x) + w1 * (y1.x + be1.x);
  o.y = r.y + w0 * (y0.y + be0.y) + w1 * (y1.y + be1.y);
  o.z = r.z + w0 * (y0.z + be0.z) + w1 * (y1.z + be1.z);
  o.w = r.w + w0 * (y0.w + be0.w) + w1 * (y1.w + be1.w);
  ((float4*)(out + (size_t)t * H_DIM))[tid] = o;
}

extern "C" void kernel_launch(void* const* d_in, const int* in_sizes, int n_in,
                              void* d_out, int out_size, void* d_ws, size_t ws_size,
                              hipStream_t stream) {
  const float* hidden = (const float*)d_in[0];
  const float* ln_w = (const float*)d_in[1];
  const float* ln_b = (const float*)d_in[2];
  const float* Wr = (const float*)d_in[3];
  const float* br = (const float*)d_in[4];
  const float* W1 = (const float*)d_in[5];
  const float* b1 = (const float*)d_in[6];
  const float* W2 = (const float*)d_in[7];
  const float* b2 = (const float*)d_in[8];
  float* out = (float*)d_out;

  // workspace layout (bytes)
  char* w = (char*)d_ws;
  int* counts = (int*)(w + 0);                    // 256 B
  int* basep = (int*)(w + 256);                   // 256 B
  float* probs = (float*)(w + 512);               // 32 KB [T_TOK][E_NUM]
  int* tlist = (int*)(w + 33280);                 // 32 KB
  int* sel_e = (int*)(w + 66048);                 // 8 KB
  int* sel_idx = (int*)(w + 74240);               // 8 KB
  float* sel_w = (float*)(w + 82432);             // 8 KB
  short* xln = (short*)(w + 98304);               // 2 MB
  short* a_buf = (short*)(w + 98304 + 2097152);   // 16 MB
  const size_t Y_OFF = 98304 + 2097152 + 16777216;  // 18972672
  float* y_part = (float*)(w + Y_OFF);            // KS * 8 MB
  const size_t Y_SZ = (size_t)NSLOT * H_DIM * 4;  // 8 MB per split set
  int lg = 2;
  while (lg > 0 && Y_OFF + (Y_SZ << lg) > ws_size) --lg;
  const int KS = 1 << lg;

  k_ln_router<<<T_TOK, 256, 0, stream>>>(hidden, ln_w, ln_b, Wr, br, xln,
                                         sel_e, sel_w, probs);
  k_route<<<1, 512, 0, stream>>>(sel_e, probs, counts, basep, tlist, sel_idx,
                                 out + (size_t)T_TOK * H_DIM);
  k_ffn1<<<dim3(I_DIM / 128, T_TOK / 128, E_NUM), 256, 0, stream>>>(
      xln, W1, b1, counts, basep, tlist, a_buf);
  k_ffn2<<<dim3(H_DIM / 128, T_TOK / 128, E_NUM << lg), 256, 0, stream>>>(
      a_buf, W2, counts, basep, y_part, lg);
  k_combine<<<T_TOK, 256, 0, stream>>>(hidden, y_part, b2, basep, sel_e, sel_idx,
                                       sel_w, out, KS);
}